// Round 17
// baseline (380.409 us; speedup 1.0000x reference)
//
#include <hip/hip_runtime.h>
#include <stdint.h>
#include <math.h>

#define BDIM   2
#define CDIM   16
#define INS    64
#define OUTS   20
#define NPTS   8000          // 20^3
#define TOTN   (BDIM*NPTS)   // 16000
#define NCHUNK 12
#define MCHUNK 668           // 11 chunks of 668 + tail 652 (both /4)
#define EPS    5e-4f         // f32 screen ambiguity band (~300x the f32 error)

// ---------------- ws layout (bytes, all 8B-aligned) ----------------
// sfeat2 (f64,-2x): 0        +2,048,000
// tfeat  (f64)    : 2048000  +2,048,000
// t2     (f64)    : 4096000  +128,000
// s2f    (f32,-2x): 4224000  +1,024,000
// tff    (f32)    : 5248000  +1,024,000
// t2f    (f32)    : 6272000  +64,000
// pmin1  (f32)    : 6336000  +768,000   (B,chunk,N)
// pmin2  (f32)    : 7104000  +768,000
// pm1    (i32)    : 7872000  +768,000
// nearest(i32)    : 8640000  +64,000
// wl     (i32)    : 8704000  +64,000
// ctr             : 8768000  +64
// lpart           : 8768064  +512
// total 8.77 MB  (< 9.03 MB proven available in round 11)

// Separable trilinear resize 64^3 -> 20^3 (jax.image.resize trilinear,
// antialias=True). Verified round 13. Now also emits f32 copies for the
// screen pass (f64 retained for the exact fallback).
__global__ __launch_bounds__(256) void k_resize(const float* __restrict__ src,
                                                const float* __restrict__ tgt,
                                                double* __restrict__ sfeat2,
                                                double* __restrict__ tfeat,
                                                float* __restrict__ s2f,
                                                float* __restrict__ tff) {
    __shared__ double wts[OUTS][8];
    __shared__ int    st[OUTS];
    __shared__ int    cnt[OUTS];
    __shared__ double plane[INS * INS];          // 32 KB
    __shared__ double hplane[OUTS * INS];        // 10 KB

    int tid = threadIdx.x;
    if (tid < OUTS) {
        double sample = (tid + 0.5) * 3.2 - 0.5;
        int lo = (int)ceil(sample - 3.2);
        int hi = (int)floor(sample + 3.2);
        if (lo < 0) lo = 0;
        if (hi > INS - 1) hi = INS - 1;
        int c = hi - lo + 1;           // <= 7
        double w[8];
        double sum = 0.0;
        for (int k = 0; k < 8; ++k) {
            double ww = 0.0;
            if (k < c) {
                double x = fabs(sample - (double)(lo + k)) * (1.0 / 3.2);
                ww = (x < 1.0) ? (1.0 - x) : 0.0;
            }
            w[k] = ww; sum += ww;
        }
        for (int k = 0; k < 8; ++k) wts[tid][k] = w[k] / sum;
        st[tid] = lo; cnt[tid] = c;
    }
    __syncthreads();

    int od  = blockIdx.x;                        // 0..19
    int c   = blockIdx.y;                        // 0..15
    int sb  = blockIdx.z;                        // 0..3
    int sel = sb >> 1;
    int b   = sb & 1;

    const float* in = (sel ? tgt : src) + (((size_t)(b * CDIM + c)) << 18);

    int sd = st[od], cd = cnt[od];
    double acc[16];
#pragma unroll
    for (int i = 0; i < 16; ++i) acc[i] = 0.0;
    for (int t = 0; t < cd; ++t) {
        double wd = wts[od][t];
        const float* p = in + (((size_t)(sd + t)) << 12) + tid;
#pragma unroll
        for (int i = 0; i < 16; ++i)
            acc[i] = fma(wd, (double)p[i << 8], acc[i]);
    }
#pragma unroll
    for (int i = 0; i < 16; ++i) plane[tid + (i << 8)] = acc[i];
    __syncthreads();

    for (int e = tid; e < OUTS * INS; e += 256) {
        int oh = e >> 6, w = e & 63;
        int sh = st[oh], ch = cnt[oh];
        double a = 0.0;
        for (int t = 0; t < ch; ++t)
            a = fma(wts[oh][t], plane[((sh + t) << 6) + w], a);
        hplane[e] = a;
    }
    __syncthreads();

    for (int e = tid; e < OUTS * OUTS; e += 256) {
        int oh = e / OUTS, ow = e - oh * OUTS;
        int sw = st[ow], cw = cnt[ow];
        const double* hp = &hplane[(oh << 6) + sw];
        double a = 0.0;
        for (int t = 0; t < cw; ++t)
            a = fma(wts[ow][t], hp[t], a);
        int n = (od * OUTS + oh) * OUTS + ow;
        size_t o = ((size_t)(b * NPTS + n)) * CDIM + c;
        if (sel == 0) {
            double v = -2.0 * a;                 // exact scale
            sfeat2[o] = v;
            s2f[o]    = (float)v;
        } else {
            tfeat[o] = a;
            tff[o]   = (float)a;
        }
    }
}

__global__ void k_t2(const double* __restrict__ tfeat, double* __restrict__ t2,
                     float* __restrict__ t2f, int* __restrict__ ctr) {
    int i = blockIdx.x * blockDim.x + threadIdx.x;
    if (i == 0) ctr[0] = 0;                      // reset worklist each launch
    if (i >= TOTN) return;
    const double* p = tfeat + (size_t)i * CDIM;
    double a = 0, b = 0, c = 0, d = 0;
#pragma unroll
    for (int k = 0; k < 4; ++k) {
        a = fma(p[4*k+0], p[4*k+0], a);
        b = fma(p[4*k+1], p[4*k+1], b);
        c = fma(p[4*k+2], p[4*k+2], c);
        d = fma(p[4*k+3], p[4*k+3], d);
    }
    double v = (a + b) + (c + d);
    t2[i]  = v;
    t2f[i] = (float)v;
}

// f32 screen: per n track (min1, argmin1, min2) over all m. T=4 n/thread,
// wave-uniform t-rows (SMEM path), waves stride-interleave m. Strict <
// keeps earliest m; ALL tie/near-tie cases widen to min2==min1 -> marked
// for the exact f64 fallback, so first-occurrence semantics are exact.
__global__ __launch_bounds__(256, 3) void k_screen(const float* __restrict__ s2f,
                                                   const float* __restrict__ tff,
                                                   const float* __restrict__ t2f,
                                                   float* __restrict__ pmin1,
                                                   float* __restrict__ pmin2,
                                                   int* __restrict__ pm1) {
    int b     = blockIdx.z;
    int chunk = blockIdx.y;
    int nbase = blockIdx.x << 8;                 // 256 n per block
    int lane  = threadIdx.x & 63;
    int wp    = (int)__builtin_amdgcn_readfirstlane(threadIdx.x >> 6);

    float s[4][16];
#pragma unroll
    for (int j = 0; j < 4; ++j) {
        int n = nbase + lane + (j << 6);
        if (n > NPTS - 1) n = NPTS - 1;          // pad clamp (writes guarded)
        const float4* sr = (const float4*)(s2f + ((size_t)(b * NPTS + n)) * CDIM);
        float4 v0 = sr[0], v1 = sr[1], v2 = sr[2], v3 = sr[3];
        s[j][0]=v0.x; s[j][1]=v0.y; s[j][2]=v0.z; s[j][3]=v0.w;
        s[j][4]=v1.x; s[j][5]=v1.y; s[j][6]=v1.z; s[j][7]=v1.w;
        s[j][8]=v2.x; s[j][9]=v2.y; s[j][10]=v2.z; s[j][11]=v2.w;
        s[j][12]=v3.x; s[j][13]=v3.y; s[j][14]=v3.z; s[j][15]=v3.w;
    }

    const float* tb  = tff + (size_t)b * NPTS * CDIM;
    const float* t2b = t2f + (size_t)b * NPTS;

    int mbase = chunk * MCHUNK;
    int mlen  = NPTS - mbase; if (mlen > MCHUNK) mlen = MCHUNK;   // 668 / 652
    int iters = mlen >> 2;

    float b1[4] = {3e38f, 3e38f, 3e38f, 3e38f};
    float b2[4] = {3e38f, 3e38f, 3e38f, 3e38f};
    int   m1[4] = {0, 0, 0, 0};
    int mstart = mbase + wp;

#pragma unroll 2
    for (int i = 0; i < iters; ++i) {
        int m = mstart + (i << 2);               // SGPR arithmetic, ascending
        const float* tr = tb + (size_t)m * CDIM;
        float t[16];
#pragma unroll
        for (int k = 0; k < CDIM; ++k) t[k] = tr[k];   // uniform -> s_load
        float tv = t2b[m];
#pragma unroll
        for (int j = 0; j < 4; ++j) {
            float d0 = 0, d1 = 0, d2 = 0, d3 = 0;
#pragma unroll
            for (int k = 0; k < 4; ++k) {
                d0 = fmaf(s[j][4*k+0], t[4*k+0], d0);
                d1 = fmaf(s[j][4*k+1], t[4*k+1], d1);
                d2 = fmaf(s[j][4*k+2], t[4*k+2], d2);
                d3 = fmaf(s[j][4*k+3], t[4*k+3], d3);
            }
            float sc = tv + ((d0 + d1) + (d2 + d3));
            if (sc < b1[j]) { b2[j] = b1[j]; b1[j] = sc; m1[j] = m; }
            else if (sc < b2[j]) b2[j] = sc;
        }
    }

    // merge the 4 waves (same 256 n) with min1/min2 bookkeeping
    __shared__ float L1[1024], L2[1024];
    __shared__ int   LM[1024];
#pragma unroll
    for (int j = 0; j < 4; ++j) {
        int e = wp * 256 + lane * 4 + j;
        L1[e] = b1[j]; L2[e] = b2[j]; LM[e] = m1[j];
    }
    __syncthreads();

    int tid = threadIdx.x;
    int e   = (tid & 63) * 4 + (tid >> 6);       // entry for n = nbase + tid
    float V1 = L1[e], V2 = L2[e];
    int   M1 = LM[e];
#pragma unroll
    for (int p = 1; p < 4; ++p) {
        float v1 = L1[p * 256 + e], v2 = L2[p * 256 + e];
        int   mm = LM[p * 256 + e];
        if (v1 < V1)       { V2 = fminf(V1, v2); V1 = v1; M1 = mm; }
        else if (v1 == V1) { V2 = V1; if (mm < M1) M1 = mm; }   // tie -> mark
        else               { V2 = fminf(V2, v1); }
    }
    int n = nbase + tid;
    if (n < NPTS) {
        size_t o = ((size_t)(b * NCHUNK + chunk)) * NPTS + n;
        pmin1[o] = V1; pmin2[o] = V2; pm1[o] = M1;
    }
}

// Merge chunk triplets (ascending chunk = ascending m); gap-test.
// Unambiguous n: nearest = M1 (f64-exact since gap > EPS >> f32 error).
// Ambiguous n: push to worklist for the exact f64 fallback.
__global__ void k_resolve(const float* __restrict__ pmin1,
                          const float* __restrict__ pmin2,
                          const int* __restrict__ pm1,
                          int* __restrict__ nearest,
                          int* __restrict__ wl, int* __restrict__ ctr) {
    int gid = blockIdx.x * 256 + threadIdx.x;
    if (gid >= TOTN) return;
    int b  = gid / NPTS;
    int nn = gid % NPTS;
    size_t o = ((size_t)(b * NCHUNK)) * NPTS + nn;
    float V1 = pmin1[o], V2 = pmin2[o];
    int   M1 = pm1[o];
    for (int c = 1; c < NCHUNK; ++c) {
        float v1 = pmin1[o + (size_t)c * NPTS], v2 = pmin2[o + (size_t)c * NPTS];
        int   mm = pm1[o + (size_t)c * NPTS];
        if (v1 < V1)       { V2 = fminf(V1, v2); V1 = v1; M1 = mm; }
        else if (v1 == V1) { V2 = V1; }          // earlier chunk keeps M1
        else               { V2 = fminf(V2, v1); }
    }
    if (V2 - V1 < EPS) {
        int k = atomicAdd(ctr, 1);
        wl[k] = gid;
    } else {
        nearest[gid] = M1;
    }
}

// Exact f64 rescan for ambiguous n: one wave per worklist entry, lanes
// stride m; strict < keeps earliest m per lane; butterfly merge is
// lexicographic (score, m) -> exact first-occurrence argmin.
__global__ __launch_bounds__(256) void k_fallback(const double* __restrict__ sfeat2,
                                                  const double* __restrict__ tfeat,
                                                  const double* __restrict__ t2,
                                                  const int* __restrict__ wl,
                                                  const int* __restrict__ ctr,
                                                  int* __restrict__ nearest) {
    int nw   = ctr[0];
    int slot = blockIdx.x * 4 + (threadIdx.x >> 6);
    int lane = threadIdx.x & 63;
    for (int k = slot; k < nw; k += gridDim.x * 4) {
        int gid = wl[k];
        int b   = gid / NPTS;
        const double* s2 = sfeat2 + (size_t)gid * CDIM;
        double s[16];
#pragma unroll
        for (int i = 0; i < 16; ++i) s[i] = s2[i];
        const double* tb  = tfeat + (size_t)b * NPTS * CDIM;
        const double* t2b = t2 + (size_t)b * NPTS;
        double best = 1e300;
        int    bm   = 0;
        for (int m = lane; m < NPTS; m += 64) {
            const double* tr = tb + (size_t)m * CDIM;
            double d0 = 0, d1 = 0, d2 = 0, d3 = 0;
#pragma unroll
            for (int kk = 0; kk < 4; ++kk) {
                d0 = fma(s[4*kk+0], tr[4*kk+0], d0);
                d1 = fma(s[4*kk+1], tr[4*kk+1], d1);
                d2 = fma(s[4*kk+2], tr[4*kk+2], d2);
                d3 = fma(s[4*kk+3], tr[4*kk+3], d3);
            }
            double sc = t2b[m] + ((d0 + d1) + (d2 + d3));
            if (sc < best) { best = sc; bm = m; }
        }
#pragma unroll
        for (int off = 1; off < 64; off <<= 1) {
            double ob = __shfl_xor(best, off, 64);
            int    om = __shfl_xor(bm,   off, 64);
            if (ob < best || (ob == best && om < bm)) { best = ob; bm = om; }
        }
        if (lane == 0) nearest[gid] = bm;
    }
}

__global__ void k_loss(const int* __restrict__ nearest,
                       const float* __restrict__ expd,
                       double* __restrict__ lpart) {
    int gid = blockIdx.x * 256 + threadIdx.x;    // 63*256 = 16128 >= 16000
    double sum = 0.0;
    if (gid < TOTN) {
        int i0 = nearest[gid];
        double fd = (double)(i0 / 400);
        double fh = (double)((i0 / 20) % 20);
        double fw = (double)(i0 % 20);
        const float* e = expd + (size_t)gid * 3;
        sum = fabs((double)e[0] - fd) + fabs((double)e[1] - fh) + fabs((double)e[2] - fw);
    }
    __shared__ double red[256];
    red[threadIdx.x] = sum;
    __syncthreads();
    for (int s = 128; s > 0; s >>= 1) {
        if (threadIdx.x < s) red[threadIdx.x] += red[threadIdx.x + s];
        __syncthreads();
    }
    if (threadIdx.x == 0) lpart[blockIdx.x] = red[0];
}

__global__ void k_final(const double* __restrict__ lpart, float* __restrict__ out) {
    int lane = threadIdx.x;                      // 64
    double v = (lane < 63) ? lpart[lane] : 0.0;
#pragma unroll
    for (int off = 32; off > 0; off >>= 1) v += __shfl_down(v, off);
    if (lane == 0) out[0] = (float)(v / 48000.0);
}

extern "C" void kernel_launch(void* const* d_in, const int* in_sizes, int n_in,
                              void* d_out, int out_size, void* d_ws, size_t ws_size,
                              hipStream_t stream) {
    const float* src  = (const float*)d_in[0];
    const float* tgt  = (const float*)d_in[1];
    const float* expd = (const float*)d_in[2];

    char* ws = (char*)d_ws;
    double* sfeat2  = (double*)(ws);
    double* tfeat   = (double*)(ws + 2048000);
    double* t2      = (double*)(ws + 4096000);
    float*  s2f     = (float*)(ws + 4224000);
    float*  tff     = (float*)(ws + 5248000);
    float*  t2f     = (float*)(ws + 6272000);
    float*  pmin1   = (float*)(ws + 6336000);
    float*  pmin2   = (float*)(ws + 7104000);
    int*    pm1     = (int*)(ws + 7872000);
    int*    nearest = (int*)(ws + 8640000);
    int*    wl      = (int*)(ws + 8704000);
    int*    ctr     = (int*)(ws + 8768000);
    double* lpart   = (double*)(ws + 8768064);

    k_resize  <<<dim3(OUTS, CDIM, 4), 256, 0, stream>>>(src, tgt, sfeat2, tfeat, s2f, tff);
    k_t2      <<<63, 256, 0, stream>>>(tfeat, t2, t2f, ctr);
    k_screen  <<<dim3(32, NCHUNK, BDIM), 256, 0, stream>>>(s2f, tff, t2f, pmin1, pmin2, pm1);
    k_resolve <<<63, 256, 0, stream>>>(pmin1, pmin2, pm1, nearest, wl, ctr);
    k_fallback<<<128, 256, 0, stream>>>(sfeat2, tfeat, t2, wl, ctr, nearest);
    k_loss    <<<63, 256, 0, stream>>>(nearest, expd, lpart);
    k_final   <<<1, 64, 0, stream>>>(lpart, (float*)d_out);
}

// Round 18
// 265.158 us; speedup vs baseline: 1.4346x; 1.4346x over previous
//
#include <hip/hip_runtime.h>
#include <stdint.h>
#include <math.h>

#define BDIM   2
#define CDIM   16
#define INS    64
#define OUTS   20
#define NPTS   8000          // 20^3
#define TOTN   (BDIM*NPTS)   // 16000
#define NCHUNK 12
#define MCHUNK 668           // 11 chunks of 668 + tail 652 (both /4)
#define EPS    5e-4f         // f32 screen ambiguity band (>10x worst f32 error)

// ---------------- ws layout (bytes, all 8B-aligned) ----------------
// sfeat2 (f64,-2x): 0        +2,048,000
// tfeat  (f64)    : 2048000  +2,048,000
// t2     (f64)    : 4096000  +128,000
// s2f    (f32,-2x): 4224000  +1,024,000
// tff    (f32)    : 5248000  +1,024,000
// t2f    (f32)    : 6272000  +64,000
// pmin1  (f32)    : 6336000  +768,000   (B,chunk,N)
// pmin2  (f32)    : 7104000  +768,000
// pm1    (i32)    : 7872000  +768,000
// nearest(i32)    : 8640000  +64,000
// wl     (i32)    : 8704000  +64,000
// ctr             : 8768000  +64
// lpart           : 8768064  +512
// total 8.77 MB

// Separable trilinear resize 64^3 -> 20^3 (jax.image.resize trilinear,
// antialias=True). Verified round 13. Emits f64 + f32 copies.
__global__ __launch_bounds__(256) void k_resize(const float* __restrict__ src,
                                                const float* __restrict__ tgt,
                                                double* __restrict__ sfeat2,
                                                double* __restrict__ tfeat,
                                                float* __restrict__ s2f,
                                                float* __restrict__ tff) {
    __shared__ double wts[OUTS][8];
    __shared__ int    st[OUTS];
    __shared__ int    cnt[OUTS];
    __shared__ double plane[INS * INS];          // 32 KB
    __shared__ double hplane[OUTS * INS];        // 10 KB

    int tid = threadIdx.x;
    if (tid < OUTS) {
        double sample = (tid + 0.5) * 3.2 - 0.5;
        int lo = (int)ceil(sample - 3.2);
        int hi = (int)floor(sample + 3.2);
        if (lo < 0) lo = 0;
        if (hi > INS - 1) hi = INS - 1;
        int c = hi - lo + 1;           // <= 7
        double w[8];
        double sum = 0.0;
        for (int k = 0; k < 8; ++k) {
            double ww = 0.0;
            if (k < c) {
                double x = fabs(sample - (double)(lo + k)) * (1.0 / 3.2);
                ww = (x < 1.0) ? (1.0 - x) : 0.0;
            }
            w[k] = ww; sum += ww;
        }
        for (int k = 0; k < 8; ++k) wts[tid][k] = w[k] / sum;
        st[tid] = lo; cnt[tid] = c;
    }
    __syncthreads();

    int od  = blockIdx.x;                        // 0..19
    int c   = blockIdx.y;                        // 0..15
    int sb  = blockIdx.z;                        // 0..3
    int sel = sb >> 1;
    int b   = sb & 1;

    const float* in = (sel ? tgt : src) + (((size_t)(b * CDIM + c)) << 18);

    int sd = st[od], cd = cnt[od];
    double acc[16];
#pragma unroll
    for (int i = 0; i < 16; ++i) acc[i] = 0.0;
    for (int t = 0; t < cd; ++t) {
        double wd = wts[od][t];
        const float* p = in + (((size_t)(sd + t)) << 12) + tid;
#pragma unroll
        for (int i = 0; i < 16; ++i)
            acc[i] = fma(wd, (double)p[i << 8], acc[i]);
    }
#pragma unroll
    for (int i = 0; i < 16; ++i) plane[tid + (i << 8)] = acc[i];
    __syncthreads();

    for (int e = tid; e < OUTS * INS; e += 256) {
        int oh = e >> 6, w = e & 63;
        int sh = st[oh], ch = cnt[oh];
        double a = 0.0;
        for (int t = 0; t < ch; ++t)
            a = fma(wts[oh][t], plane[((sh + t) << 6) + w], a);
        hplane[e] = a;
    }
    __syncthreads();

    for (int e = tid; e < OUTS * OUTS; e += 256) {
        int oh = e / OUTS, ow = e - oh * OUTS;
        int sw = st[ow], cw = cnt[ow];
        const double* hp = &hplane[(oh << 6) + sw];
        double a = 0.0;
        for (int t = 0; t < cw; ++t)
            a = fma(wts[ow][t], hp[t], a);
        int n = (od * OUTS + oh) * OUTS + ow;
        size_t o = ((size_t)(b * NPTS + n)) * CDIM + c;
        if (sel == 0) {
            double v = -2.0 * a;                 // exact scale
            sfeat2[o] = v;
            s2f[o]    = (float)v;
        } else {
            tfeat[o] = a;
            tff[o]   = (float)a;
        }
    }
}

__global__ void k_t2(const double* __restrict__ tfeat, double* __restrict__ t2,
                     float* __restrict__ t2f, int* __restrict__ ctr) {
    int i = blockIdx.x * blockDim.x + threadIdx.x;
    if (i == 0) ctr[0] = 0;                      // reset worklist each launch
    if (i >= TOTN) return;
    const double* p = tfeat + (size_t)i * CDIM;
    double a = 0, b = 0, c = 0, d = 0;
#pragma unroll
    for (int k = 0; k < 4; ++k) {
        a = fma(p[4*k+0], p[4*k+0], a);
        b = fma(p[4*k+1], p[4*k+1], b);
        c = fma(p[4*k+2], p[4*k+2], c);
        d = fma(p[4*k+3], p[4*k+3], d);
    }
    double v = (a + b) + (c + d);
    t2[i]  = v;
    t2f[i] = (float)v;
}

// f32 screen with round-10-style ping-pong prefetch: SMEM t-loads for the
// next iteration are issued before the current body, so s_load latency
// hides under the FMA burst (round 17 was serially latency-bound).
// Arithmetic and tie handling unchanged -> identical screen results.
__global__ __launch_bounds__(256, 3) void k_screen(const float* __restrict__ s2f,
                                                   const float* __restrict__ tff,
                                                   const float* __restrict__ t2f,
                                                   float* __restrict__ pmin1,
                                                   float* __restrict__ pmin2,
                                                   int* __restrict__ pm1) {
    int b     = blockIdx.z;
    int chunk = blockIdx.y;
    int nbase = blockIdx.x << 8;                 // 256 n per block
    int lane  = threadIdx.x & 63;
    int wp    = (int)__builtin_amdgcn_readfirstlane(threadIdx.x >> 6);

    float s[4][16];
#pragma unroll
    for (int j = 0; j < 4; ++j) {
        int n = nbase + lane + (j << 6);
        if (n > NPTS - 1) n = NPTS - 1;          // pad clamp (writes guarded)
        const float4* sr = (const float4*)(s2f + ((size_t)(b * NPTS + n)) * CDIM);
        float4 v0 = sr[0], v1 = sr[1], v2 = sr[2], v3 = sr[3];
        s[j][0]=v0.x; s[j][1]=v0.y; s[j][2]=v0.z; s[j][3]=v0.w;
        s[j][4]=v1.x; s[j][5]=v1.y; s[j][6]=v1.z; s[j][7]=v1.w;
        s[j][8]=v2.x; s[j][9]=v2.y; s[j][10]=v2.z; s[j][11]=v2.w;
        s[j][12]=v3.x; s[j][13]=v3.y; s[j][14]=v3.z; s[j][15]=v3.w;
    }

    const float* tb  = tff + (size_t)b * NPTS * CDIM;
    const float* t2b = t2f + (size_t)b * NPTS;

    int mbase = chunk * MCHUNK;
    int mlen  = NPTS - mbase; if (mlen > MCHUNK) mlen = MCHUNK;   // 668 / 652
    int iters = mlen >> 2;
    int mstart = mbase + wp;

    float b1[4] = {3e38f, 3e38f, 3e38f, 3e38f};
    float b2[4] = {3e38f, 3e38f, 3e38f, 3e38f};
    int   m1[4] = {0, 0, 0, 0};

    float tE[16], tO[16], tvE, tvO;

#define LOADT(I, T, TV)                                            \
    {  int m_ = mstart + ((I) << 2);                               \
       const float* tr_ = tb + (size_t)m_ * CDIM;                  \
       _Pragma("unroll")                                           \
       for (int kk = 0; kk < 16; ++kk) T[kk] = tr_[kk];            \
       TV = t2b[m_]; }

#define BODYT(I, T, TV)                                            \
    {  int m_ = mstart + ((I) << 2);                               \
       _Pragma("unroll")                                           \
       for (int j = 0; j < 4; ++j) {                               \
           float d0 = 0, d1 = 0, d2 = 0, d3 = 0;                   \
           _Pragma("unroll")                                       \
           for (int k = 0; k < 4; ++k) {                           \
               d0 = fmaf(s[j][4*k+0], T[4*k+0], d0);               \
               d1 = fmaf(s[j][4*k+1], T[4*k+1], d1);               \
               d2 = fmaf(s[j][4*k+2], T[4*k+2], d2);               \
               d3 = fmaf(s[j][4*k+3], T[4*k+3], d3);               \
           }                                                       \
           float sc = TV + ((d0 + d1) + (d2 + d3));                \
           if (sc < b1[j]) { b2[j] = b1[j]; b1[j] = sc; m1[j] = m_; } \
           else if (sc < b2[j]) b2[j] = sc;                        \
       } }

    LOADT(0, tE, tvE);
    if (iters > 1) LOADT(1, tO, tvO);

    int p = 0;
    for (; p + 2 < iters; p += 2) {
        BODYT(p, tE, tvE);
        LOADT(p + 2, tE, tvE);
        BODYT(p + 1, tO, tvO);
        if (p + 3 < iters) LOADT(p + 3, tO, tvO);
    }
    BODYT(p, tE, tvE);
    if (p + 1 < iters) BODYT(p + 1, tO, tvO);

#undef LOADT
#undef BODYT

    // merge the 4 waves (same 256 n) with min1/min2 bookkeeping
    __shared__ float L1[1024], L2[1024];
    __shared__ int   LM[1024];
#pragma unroll
    for (int j = 0; j < 4; ++j) {
        int e = wp * 256 + lane * 4 + j;
        L1[e] = b1[j]; L2[e] = b2[j]; LM[e] = m1[j];
    }
    __syncthreads();

    int tid = threadIdx.x;
    int e   = (tid & 63) * 4 + (tid >> 6);       // entry for n = nbase + tid
    float V1 = L1[e], V2 = L2[e];
    int   M1 = LM[e];
#pragma unroll
    for (int q = 1; q < 4; ++q) {
        float v1 = L1[q * 256 + e], v2 = L2[q * 256 + e];
        int   mm = LM[q * 256 + e];
        if (v1 < V1)       { V2 = fminf(V1, v2); V1 = v1; M1 = mm; }
        else if (v1 == V1) { V2 = V1; if (mm < M1) M1 = mm; }   // tie -> mark
        else               { V2 = fminf(V2, v1); }
    }
    int n = nbase + tid;
    if (n < NPTS) {
        size_t o = ((size_t)(b * NCHUNK + chunk)) * NPTS + n;
        pmin1[o] = V1; pmin2[o] = V2; pm1[o] = M1;
    }
}

// Merge chunk triplets (ascending chunk = ascending m); gap-test.
__global__ void k_resolve(const float* __restrict__ pmin1,
                          const float* __restrict__ pmin2,
                          const int* __restrict__ pm1,
                          int* __restrict__ nearest,
                          int* __restrict__ wl, int* __restrict__ ctr) {
    int gid = blockIdx.x * 256 + threadIdx.x;
    if (gid >= TOTN) return;
    int b  = gid / NPTS;
    int nn = gid % NPTS;
    size_t o = ((size_t)(b * NCHUNK)) * NPTS + nn;
    float V1 = pmin1[o], V2 = pmin2[o];
    int   M1 = pm1[o];
    for (int c = 1; c < NCHUNK; ++c) {
        float v1 = pmin1[o + (size_t)c * NPTS], v2 = pmin2[o + (size_t)c * NPTS];
        int   mm = pm1[o + (size_t)c * NPTS];
        if (v1 < V1)       { V2 = fminf(V1, v2); V1 = v1; M1 = mm; }
        else if (v1 == V1) { V2 = V1; }          // earlier chunk keeps M1
        else               { V2 = fminf(V2, v1); }
    }
    if (V2 - V1 < EPS) {
        int k = atomicAdd(ctr, 1);
        wl[k] = gid;
    } else {
        nearest[gid] = M1;
    }
}

// Exact f64 rescan for ambiguous n — BLOCK-per-entry (round 17 used one
// wave per entry with no pipelining: 229 us latency-bound). 256 threads
// stride m (31 full iters + 64-lane tail), s broadcast from LDS, ping-pong
// prefetch, lexicographic LDS tree reduce -> exact first-occurrence argmin.
__global__ __launch_bounds__(256) void k_fallback(const double* __restrict__ sfeat2,
                                                  const double* __restrict__ tfeat,
                                                  const double* __restrict__ t2,
                                                  const int* __restrict__ wl,
                                                  const int* __restrict__ ctr,
                                                  int* __restrict__ nearest) {
    __shared__ double sS[16];
    __shared__ double red[256];
    __shared__ int    redm[256];
    int nw  = ctr[0];
    int tid = threadIdx.x;

    for (int k = blockIdx.x; k < nw; k += gridDim.x) {
        int gid = wl[k];
        int b   = gid / NPTS;
        if (tid < 16) sS[tid] = sfeat2[(size_t)gid * CDIM + tid];
        __syncthreads();
        double sR[16];
#pragma unroll
        for (int i = 0; i < 16; ++i) sR[i] = sS[i];

        const double* tb  = tfeat + (size_t)b * NPTS * CDIM;
        const double* t2b = t2 + (size_t)b * NPTS;

        double best = 1e300;
        int    bm   = 0;
        double tEr[16], tOr[16], tvE, tvO;

#define LOADM(M, T, TV)                                            \
    {  const double* tr_ = tb + (size_t)(M) * CDIM;                \
       _Pragma("unroll")                                           \
       for (int kk = 0; kk < 16; ++kk) T[kk] = tr_[kk];            \
       TV = t2b[(M)]; }

#define BODYM(M, T, TV)                                            \
    {  double d0 = 0, d1 = 0, d2 = 0, d3 = 0;                      \
       _Pragma("unroll")                                           \
       for (int kk = 0; kk < 4; ++kk) {                            \
           d0 = fma(sR[4*kk+0], T[4*kk+0], d0);                    \
           d1 = fma(sR[4*kk+1], T[4*kk+1], d1);                    \
           d2 = fma(sR[4*kk+2], T[4*kk+2], d2);                    \
           d3 = fma(sR[4*kk+3], T[4*kk+3], d3);                    \
       }                                                           \
       double sc = TV + ((d0 + d1) + (d2 + d3));                   \
       if (sc < best) { best = sc; bm = (M); } }

        // 31 full iterations: m = tid + 256*i  (m ascending per thread)
        LOADM(tid, tEr, tvE);
        LOADM(tid + 256, tOr, tvO);
        int i = 0;
        for (; i + 2 < 31; i += 2) {
            BODYM(tid + (i << 8), tEr, tvE);
            LOADM(tid + ((i + 2) << 8), tEr, tvE);
            BODYM(tid + ((i + 1) << 8), tOr, tvO);
            if (i + 3 < 31) LOADM(tid + ((i + 3) << 8), tOr, tvO);
        }
        BODYM(tid + (i << 8), tEr, tvE);
        BODYM(tid + ((i + 1) << 8), tOr, tvO);
        if (tid < 64) {                          // tail m = 7936 + tid
            LOADM(7936 + tid, tEr, tvE);
            BODYM(7936 + tid, tEr, tvE);
        }

#undef LOADM
#undef BODYM

        red[tid] = best; redm[tid] = bm;
        __syncthreads();
        for (int s = 128; s > 0; s >>= 1) {
            if (tid < s) {
                double ob = red[tid + s]; int om = redm[tid + s];
                if (ob < red[tid] || (ob == red[tid] && om < redm[tid])) {
                    red[tid] = ob; redm[tid] = om;
                }
            }
            __syncthreads();
        }
        if (tid == 0) nearest[gid] = redm[0];
        __syncthreads();                         // protect sS for next k
    }
}

__global__ void k_loss(const int* __restrict__ nearest,
                       const float* __restrict__ expd,
                       double* __restrict__ lpart) {
    int gid = blockIdx.x * 256 + threadIdx.x;    // 63*256 = 16128 >= 16000
    double sum = 0.0;
    if (gid < TOTN) {
        int i0 = nearest[gid];
        double fd = (double)(i0 / 400);
        double fh = (double)((i0 / 20) % 20);
        double fw = (double)(i0 % 20);
        const float* e = expd + (size_t)gid * 3;
        sum = fabs((double)e[0] - fd) + fabs((double)e[1] - fh) + fabs((double)e[2] - fw);
    }
    __shared__ double red[256];
    red[threadIdx.x] = sum;
    __syncthreads();
    for (int s = 128; s > 0; s >>= 1) {
        if (threadIdx.x < s) red[threadIdx.x] += red[threadIdx.x + s];
        __syncthreads();
    }
    if (threadIdx.x == 0) lpart[blockIdx.x] = red[0];
}

__global__ void k_final(const double* __restrict__ lpart, float* __restrict__ out) {
    int lane = threadIdx.x;                      // 64
    double v = (lane < 63) ? lpart[lane] : 0.0;
#pragma unroll
    for (int off = 32; off > 0; off >>= 1) v += __shfl_down(v, off);
    if (lane == 0) out[0] = (float)(v / 48000.0);
}

extern "C" void kernel_launch(void* const* d_in, const int* in_sizes, int n_in,
                              void* d_out, int out_size, void* d_ws, size_t ws_size,
                              hipStream_t stream) {
    const float* src  = (const float*)d_in[0];
    const float* tgt  = (const float*)d_in[1];
    const float* expd = (const float*)d_in[2];

    char* ws = (char*)d_ws;
    double* sfeat2  = (double*)(ws);
    double* tfeat   = (double*)(ws + 2048000);
    double* t2      = (double*)(ws + 4096000);
    float*  s2f     = (float*)(ws + 4224000);
    float*  tff     = (float*)(ws + 5248000);
    float*  t2f     = (float*)(ws + 6272000);
    float*  pmin1   = (float*)(ws + 6336000);
    float*  pmin2   = (float*)(ws + 7104000);
    int*    pm1     = (int*)(ws + 7872000);
    int*    nearest = (int*)(ws + 8640000);
    int*    wl      = (int*)(ws + 8704000);
    int*    ctr     = (int*)(ws + 8768000);
    double* lpart   = (double*)(ws + 8768064);

    k_resize  <<<dim3(OUTS, CDIM, 4), 256, 0, stream>>>(src, tgt, sfeat2, tfeat, s2f, tff);
    k_t2      <<<63, 256, 0, stream>>>(tfeat, t2, t2f, ctr);
    k_screen  <<<dim3(32, NCHUNK, BDIM), 256, 0, stream>>>(s2f, tff, t2f, pmin1, pmin2, pm1);
    k_resolve <<<63, 256, 0, stream>>>(pmin1, pmin2, pm1, nearest, wl, ctr);
    k_fallback<<<1024, 256, 0, stream>>>(sfeat2, tfeat, t2, wl, ctr, nearest);
    k_loss    <<<63, 256, 0, stream>>>(nearest, expd, lpart);
    k_final   <<<1, 64, 0, stream>>>(lpart, (float*)d_out);
}

// Round 19
// 178.779 us; speedup vs baseline: 2.1278x; 1.4832x over previous
//
#include <hip/hip_runtime.h>
#include <stdint.h>
#include <math.h>

#define BDIM   2
#define CDIM   16
#define INS    64
#define OUTS   20
#define NPTS   8000          // 20^3
#define TOTN   (BDIM*NPTS)   // 16000
#define NCHUNK 12
#define MCHUNK 668           // 11 chunks of 668 + tail 652 (both /4)
#define EPS    1e-4f         // f32 screen ambiguity band (>=10x worst f32 error)

// ---------------- ws layout (bytes, all 8B-aligned) ----------------
// sfeat2 (f64,-2x): 0        +2,048,000
// tfeat  (f64)    : 2048000  +2,048,000
// t2     (f64)    : 4096000  +128,000
// s2f    (f32,-2x): 4224000  +1,024,000
// tff    (f32)    : 5248000  +1,024,000
// t2f    (f32)    : 6272000  +64,000
// pmin1  (f32)    : 6336000  +768,000   (B,chunk,N)
// pmin2  (f32)    : 7104000  +768,000
// pm1    (i32)    : 7872000  +768,000
// nearest(i32)    : 8640000  +64,000
// wl     (i32)    : 8704000  +64,000
// ctr             : 8768000  +64
// lpart           : 8768064  +512
// total 8.77 MB

// Separable trilinear resize 64^3 -> 20^3 (jax.image.resize trilinear,
// antialias=True). Verified round 13. Emits f64 + f32 copies.
__global__ __launch_bounds__(256) void k_resize(const float* __restrict__ src,
                                                const float* __restrict__ tgt,
                                                double* __restrict__ sfeat2,
                                                double* __restrict__ tfeat,
                                                float* __restrict__ s2f,
                                                float* __restrict__ tff) {
    __shared__ double wts[OUTS][8];
    __shared__ int    st[OUTS];
    __shared__ int    cnt[OUTS];
    __shared__ double plane[INS * INS];          // 32 KB
    __shared__ double hplane[OUTS * INS];        // 10 KB

    int tid = threadIdx.x;
    if (tid < OUTS) {
        double sample = (tid + 0.5) * 3.2 - 0.5;
        int lo = (int)ceil(sample - 3.2);
        int hi = (int)floor(sample + 3.2);
        if (lo < 0) lo = 0;
        if (hi > INS - 1) hi = INS - 1;
        int c = hi - lo + 1;           // <= 7
        double w[8];
        double sum = 0.0;
        for (int k = 0; k < 8; ++k) {
            double ww = 0.0;
            if (k < c) {
                double x = fabs(sample - (double)(lo + k)) * (1.0 / 3.2);
                ww = (x < 1.0) ? (1.0 - x) : 0.0;
            }
            w[k] = ww; sum += ww;
        }
        for (int k = 0; k < 8; ++k) wts[tid][k] = w[k] / sum;
        st[tid] = lo; cnt[tid] = c;
    }
    __syncthreads();

    int od  = blockIdx.x;                        // 0..19
    int c   = blockIdx.y;                        // 0..15
    int sb  = blockIdx.z;                        // 0..3
    int sel = sb >> 1;
    int b   = sb & 1;

    const float* in = (sel ? tgt : src) + (((size_t)(b * CDIM + c)) << 18);

    int sd = st[od], cd = cnt[od];
    double acc[16];
#pragma unroll
    for (int i = 0; i < 16; ++i) acc[i] = 0.0;
    for (int t = 0; t < cd; ++t) {
        double wd = wts[od][t];
        const float* p = in + (((size_t)(sd + t)) << 12) + tid;
#pragma unroll
        for (int i = 0; i < 16; ++i)
            acc[i] = fma(wd, (double)p[i << 8], acc[i]);
    }
#pragma unroll
    for (int i = 0; i < 16; ++i) plane[tid + (i << 8)] = acc[i];
    __syncthreads();

    for (int e = tid; e < OUTS * INS; e += 256) {
        int oh = e >> 6, w = e & 63;
        int sh = st[oh], ch = cnt[oh];
        double a = 0.0;
        for (int t = 0; t < ch; ++t)
            a = fma(wts[oh][t], plane[((sh + t) << 6) + w], a);
        hplane[e] = a;
    }
    __syncthreads();

    for (int e = tid; e < OUTS * OUTS; e += 256) {
        int oh = e / OUTS, ow = e - oh * OUTS;
        int sw = st[ow], cw = cnt[ow];
        const double* hp = &hplane[(oh << 6) + sw];
        double a = 0.0;
        for (int t = 0; t < cw; ++t)
            a = fma(wts[ow][t], hp[t], a);
        int n = (od * OUTS + oh) * OUTS + ow;
        size_t o = ((size_t)(b * NPTS + n)) * CDIM + c;
        if (sel == 0) {
            double v = -2.0 * a;                 // exact scale
            sfeat2[o] = v;
            s2f[o]    = (float)v;
        } else {
            tfeat[o] = a;
            tff[o]   = (float)a;
        }
    }
}

__global__ void k_t2(const double* __restrict__ tfeat, double* __restrict__ t2,
                     float* __restrict__ t2f, int* __restrict__ ctr) {
    int i = blockIdx.x * blockDim.x + threadIdx.x;
    if (i == 0) ctr[0] = 0;                      // reset worklist each launch
    if (i >= TOTN) return;
    const double* p = tfeat + (size_t)i * CDIM;
    double a = 0, b = 0, c = 0, d = 0;
#pragma unroll
    for (int k = 0; k < 4; ++k) {
        a = fma(p[4*k+0], p[4*k+0], a);
        b = fma(p[4*k+1], p[4*k+1], b);
        c = fma(p[4*k+2], p[4*k+2], c);
        d = fma(p[4*k+3], p[4*k+3], d);
    }
    double v = (a + b) + (c + d);
    t2[i]  = v;
    t2f[i] = (float)v;
}

// f32 screen with ping-pong SMEM prefetch (round-18, verified exact).
__global__ __launch_bounds__(256, 3) void k_screen(const float* __restrict__ s2f,
                                                   const float* __restrict__ tff,
                                                   const float* __restrict__ t2f,
                                                   float* __restrict__ pmin1,
                                                   float* __restrict__ pmin2,
                                                   int* __restrict__ pm1) {
    int b     = blockIdx.z;
    int chunk = blockIdx.y;
    int nbase = blockIdx.x << 8;                 // 256 n per block
    int lane  = threadIdx.x & 63;
    int wp    = (int)__builtin_amdgcn_readfirstlane(threadIdx.x >> 6);

    float s[4][16];
#pragma unroll
    for (int j = 0; j < 4; ++j) {
        int n = nbase + lane + (j << 6);
        if (n > NPTS - 1) n = NPTS - 1;          // pad clamp (writes guarded)
        const float4* sr = (const float4*)(s2f + ((size_t)(b * NPTS + n)) * CDIM);
        float4 v0 = sr[0], v1 = sr[1], v2 = sr[2], v3 = sr[3];
        s[j][0]=v0.x; s[j][1]=v0.y; s[j][2]=v0.z; s[j][3]=v0.w;
        s[j][4]=v1.x; s[j][5]=v1.y; s[j][6]=v1.z; s[j][7]=v1.w;
        s[j][8]=v2.x; s[j][9]=v2.y; s[j][10]=v2.z; s[j][11]=v2.w;
        s[j][12]=v3.x; s[j][13]=v3.y; s[j][14]=v3.z; s[j][15]=v3.w;
    }

    const float* tb  = tff + (size_t)b * NPTS * CDIM;
    const float* t2b = t2f + (size_t)b * NPTS;

    int mbase = chunk * MCHUNK;
    int mlen  = NPTS - mbase; if (mlen > MCHUNK) mlen = MCHUNK;   // 668 / 652
    int iters = mlen >> 2;
    int mstart = mbase + wp;

    float b1[4] = {3e38f, 3e38f, 3e38f, 3e38f};
    float b2[4] = {3e38f, 3e38f, 3e38f, 3e38f};
    int   m1[4] = {0, 0, 0, 0};

    float tE[16], tO[16], tvE, tvO;

#define LOADT(I, T, TV)                                            \
    {  int m_ = mstart + ((I) << 2);                               \
       const float* tr_ = tb + (size_t)m_ * CDIM;                  \
       _Pragma("unroll")                                           \
       for (int kk = 0; kk < 16; ++kk) T[kk] = tr_[kk];            \
       TV = t2b[m_]; }

#define BODYT(I, T, TV)                                            \
    {  int m_ = mstart + ((I) << 2);                               \
       _Pragma("unroll")                                           \
       for (int j = 0; j < 4; ++j) {                               \
           float d0 = 0, d1 = 0, d2 = 0, d3 = 0;                   \
           _Pragma("unroll")                                       \
           for (int k = 0; k < 4; ++k) {                           \
               d0 = fmaf(s[j][4*k+0], T[4*k+0], d0);               \
               d1 = fmaf(s[j][4*k+1], T[4*k+1], d1);               \
               d2 = fmaf(s[j][4*k+2], T[4*k+2], d2);               \
               d3 = fmaf(s[j][4*k+3], T[4*k+3], d3);               \
           }                                                       \
           float sc = TV + ((d0 + d1) + (d2 + d3));                \
           if (sc < b1[j]) { b2[j] = b1[j]; b1[j] = sc; m1[j] = m_; } \
           else if (sc < b2[j]) b2[j] = sc;                        \
       } }

    LOADT(0, tE, tvE);
    if (iters > 1) LOADT(1, tO, tvO);

    int p = 0;
    for (; p + 2 < iters; p += 2) {
        BODYT(p, tE, tvE);
        LOADT(p + 2, tE, tvE);
        BODYT(p + 1, tO, tvO);
        if (p + 3 < iters) LOADT(p + 3, tO, tvO);
    }
    BODYT(p, tE, tvE);
    if (p + 1 < iters) BODYT(p + 1, tO, tvO);

#undef LOADT
#undef BODYT

    // merge the 4 waves (same 256 n) with min1/min2 bookkeeping
    __shared__ float L1[1024], L2[1024];
    __shared__ int   LM[1024];
#pragma unroll
    for (int j = 0; j < 4; ++j) {
        int e = wp * 256 + lane * 4 + j;
        L1[e] = b1[j]; L2[e] = b2[j]; LM[e] = m1[j];
    }
    __syncthreads();

    int tid = threadIdx.x;
    int e   = (tid & 63) * 4 + (tid >> 6);       // entry for n = nbase + tid
    float V1 = L1[e], V2 = L2[e];
    int   M1 = LM[e];
#pragma unroll
    for (int q = 1; q < 4; ++q) {
        float v1 = L1[q * 256 + e], v2 = L2[q * 256 + e];
        int   mm = LM[q * 256 + e];
        if (v1 < V1)       { V2 = fminf(V1, v2); V1 = v1; M1 = mm; }
        else if (v1 == V1) { V2 = V1; if (mm < M1) M1 = mm; }   // tie -> mark
        else               { V2 = fminf(V2, v1); }
    }
    int n = nbase + tid;
    if (n < NPTS) {
        size_t o = ((size_t)(b * NCHUNK + chunk)) * NPTS + n;
        pmin1[o] = V1; pmin2[o] = V2; pm1[o] = M1;
    }
}

// Merge chunk triplets (ascending chunk = ascending m); gap-test.
__global__ void k_resolve(const float* __restrict__ pmin1,
                          const float* __restrict__ pmin2,
                          const int* __restrict__ pm1,
                          int* __restrict__ nearest,
                          int* __restrict__ wl, int* __restrict__ ctr) {
    int gid = blockIdx.x * 256 + threadIdx.x;
    if (gid >= TOTN) return;
    int b  = gid / NPTS;
    int nn = gid % NPTS;
    size_t o = ((size_t)(b * NCHUNK)) * NPTS + nn;
    float V1 = pmin1[o], V2 = pmin2[o];
    int   M1 = pm1[o];
    for (int c = 1; c < NCHUNK; ++c) {
        float v1 = pmin1[o + (size_t)c * NPTS], v2 = pmin2[o + (size_t)c * NPTS];
        int   mm = pm1[o + (size_t)c * NPTS];
        if (v1 < V1)       { V2 = fminf(V1, v2); V1 = v1; M1 = mm; }
        else if (v1 == V1) { V2 = V1; }          // earlier chunk keeps M1
        else               { V2 = fminf(V2, v1); }
    }
    if (V2 - V1 < EPS) {
        int k = atomicAdd(ctr, 1);
        wl[k] = gid;
    } else {
        nearest[gid] = M1;
    }
}

// Exact f64 rescan for ambiguous n — block-per-entry with LDS-STAGED t-rows.
// Round 18's per-lane row reads touched 64 cache lines per wave-load (stride
// 128 B) -> ~2k L2 transactions/block-iter = 9.5k cy/iter. Now the block
// stages each 256-row (32 KB) slab coalesced (lane-consecutive 16 B chunks,
// 8 lines per wave-load) into LDS (17-f64 row pitch -> 2-way-conflict reads,
// free), then each thread dots its own row from LDS. Exact lexicographic
// (score, m) reduce; per-thread m ascends so strict < keeps earliest m.
__global__ __launch_bounds__(256) void k_fallback(const double* __restrict__ sfeat2,
                                                  const double* __restrict__ tfeat,
                                                  const double* __restrict__ t2,
                                                  const int* __restrict__ wl,
                                                  const int* __restrict__ ctr,
                                                  int* __restrict__ nearest) {
    __shared__ double tile[256 * 17];            // 34 KB
    __shared__ double sS[16];
    __shared__ double red[256];
    __shared__ int    redm[256];
    int nw  = ctr[0];
    int tid = threadIdx.x;

    for (int k = blockIdx.x; k < nw; k += gridDim.x) {
        int gid = wl[k];
        int b   = gid / NPTS;
        __syncthreads();                         // protect sS/tile across k
        if (tid < 16) sS[tid] = sfeat2[(size_t)gid * CDIM + tid];
        __syncthreads();
        double sR[16];
#pragma unroll
        for (int i = 0; i < 16; ++i) sR[i] = sS[i];

        const double* tb  = tfeat + (size_t)b * NPTS * CDIM;
        const double* t2b = t2 + (size_t)b * NPTS;

        double best = 1e300;
        int    bm   = 0;

        for (int ti = 0; ti < 31; ++ti) {
            int base = ti << 8;                  // 256 rows per tile
            const double* src_ = tb + (size_t)base * CDIM;
            __syncthreads();                     // prior tile reads done
#pragma unroll
            for (int j = 0; j < 8; ++j) {
                int of = (tid << 1) + (j << 9);  // f64 units, coalesced
                int r  = of >> 4, c = of & 15;
                double2 v = *(const double2*)(src_ + of);
                tile[r * 17 + c]     = v.x;
                tile[r * 17 + c + 1] = v.y;
            }
            __syncthreads();
            const double* tr = &tile[tid * 17];  // this thread's row: m=base+tid
            double d0 = 0, d1 = 0, d2 = 0, d3 = 0;
#pragma unroll
            for (int kk = 0; kk < 4; ++kk) {
                d0 = fma(sR[4*kk+0], tr[4*kk+0], d0);
                d1 = fma(sR[4*kk+1], tr[4*kk+1], d1);
                d2 = fma(sR[4*kk+2], tr[4*kk+2], d2);
                d3 = fma(sR[4*kk+3], tr[4*kk+3], d3);
            }
            double sc = t2b[base + tid] + ((d0 + d1) + (d2 + d3));
            if (sc < best) { best = sc; bm = base + tid; }
        }
        // tail m in [7936, 8000): 64 rows, one-off direct reads
        if (tid < 64) {
            int m = 7936 + tid;
            const double* tr = tb + (size_t)m * CDIM;
            double d0 = 0, d1 = 0, d2 = 0, d3 = 0;
#pragma unroll
            for (int kk = 0; kk < 4; ++kk) {
                d0 = fma(sR[4*kk+0], tr[4*kk+0], d0);
                d1 = fma(sR[4*kk+1], tr[4*kk+1], d1);
                d2 = fma(sR[4*kk+2], tr[4*kk+2], d2);
                d3 = fma(sR[4*kk+3], tr[4*kk+3], d3);
            }
            double sc = t2b[m] + ((d0 + d1) + (d2 + d3));
            if (sc < best) { best = sc; bm = m; }
        }

        red[tid] = best; redm[tid] = bm;
        __syncthreads();
        for (int s = 128; s > 0; s >>= 1) {
            if (tid < s) {
                double ob = red[tid + s]; int om = redm[tid + s];
                if (ob < red[tid] || (ob == red[tid] && om < redm[tid])) {
                    red[tid] = ob; redm[tid] = om;
                }
            }
            __syncthreads();
        }
        if (tid == 0) nearest[gid] = redm[0];
    }
}

__global__ void k_loss(const int* __restrict__ nearest,
                       const float* __restrict__ expd,
                       double* __restrict__ lpart) {
    int gid = blockIdx.x * 256 + threadIdx.x;    // 63*256 = 16128 >= 16000
    double sum = 0.0;
    if (gid < TOTN) {
        int i0 = nearest[gid];
        double fd = (double)(i0 / 400);
        double fh = (double)((i0 / 20) % 20);
        double fw = (double)(i0 % 20);
        const float* e = expd + (size_t)gid * 3;
        sum = fabs((double)e[0] - fd) + fabs((double)e[1] - fh) + fabs((double)e[2] - fw);
    }
    __shared__ double red[256];
    red[threadIdx.x] = sum;
    __syncthreads();
    for (int s = 128; s > 0; s >>= 1) {
        if (threadIdx.x < s) red[threadIdx.x] += red[threadIdx.x + s];
        __syncthreads();
    }
    if (threadIdx.x == 0) lpart[blockIdx.x] = red[0];
}

__global__ void k_final(const double* __restrict__ lpart, float* __restrict__ out) {
    int lane = threadIdx.x;                      // 64
    double v = (lane < 63) ? lpart[lane] : 0.0;
#pragma unroll
    for (int off = 32; off > 0; off >>= 1) v += __shfl_down(v, off);
    if (lane == 0) out[0] = (float)(v / 48000.0);
}

extern "C" void kernel_launch(void* const* d_in, const int* in_sizes, int n_in,
                              void* d_out, int out_size, void* d_ws, size_t ws_size,
                              hipStream_t stream) {
    const float* src  = (const float*)d_in[0];
    const float* tgt  = (const float*)d_in[1];
    const float* expd = (const float*)d_in[2];

    char* ws = (char*)d_ws;
    double* sfeat2  = (double*)(ws);
    double* tfeat   = (double*)(ws + 2048000);
    double* t2      = (double*)(ws + 4096000);
    float*  s2f     = (float*)(ws + 4224000);
    float*  tff     = (float*)(ws + 5248000);
    float*  t2f     = (float*)(ws + 6272000);
    float*  pmin1   = (float*)(ws + 6336000);
    float*  pmin2   = (float*)(ws + 7104000);
    int*    pm1     = (int*)(ws + 7872000);
    int*    nearest = (int*)(ws + 8640000);
    int*    wl      = (int*)(ws + 8704000);
    int*    ctr     = (int*)(ws + 8768000);
    double* lpart   = (double*)(ws + 8768064);

    k_resize  <<<dim3(OUTS, CDIM, 4), 256, 0, stream>>>(src, tgt, sfeat2, tfeat, s2f, tff);
    k_t2      <<<63, 256, 0, stream>>>(tfeat, t2, t2f, ctr);
    k_screen  <<<dim3(32, NCHUNK, BDIM), 256, 0, stream>>>(s2f, tff, t2f, pmin1, pmin2, pm1);
    k_resolve <<<63, 256, 0, stream>>>(pmin1, pmin2, pm1, nearest, wl, ctr);
    k_fallback<<<1024, 256, 0, stream>>>(sfeat2, tfeat, t2, wl, ctr, nearest);
    k_loss    <<<63, 256, 0, stream>>>(nearest, expd, lpart);
    k_final   <<<1, 64, 0, stream>>>(lpart, (float*)d_out);
}